// Round 1
// baseline (110.410 us; speedup 1.0000x reference)
//
#include <hip/hip_runtime.h>

#define B_  4
#define C_  256
#define H_IN 128
#define W_IN 128
#define H2 (2*H_IN)
#define W2 (2*W_IN)
#define QPR (W2/4)          // quads per output row = 64

__global__ __launch_bounds__(256) void upfir_up2_kernel(
    const float* __restrict__ x, float* __restrict__ out, int nQuads)
{
    const int stride = gridDim.x * blockDim.x;
    for (int q = blockIdx.x * blockDim.x + threadIdx.x; q < nQuads; q += stride) {
        const int qx = q & (QPR - 1);          // 0..63
        const int y  = (q >> 6) & (H2 - 1);    // 0..255
        const int bc = q >> 14;                // 0..1023
        const int c0 = qx * 2;                 // base input col
        const int py = y & 1;

        // vertical taps
        int ra = (y >> 1) - 1 + py;
        int rb = ra + 1;
        float wyA = py ? 3.f : 1.f;
        float wyB = py ? 1.f : 3.f;
        if (ra < 0)        { ra = 0;        wyA = 0.f; }
        if (rb > H_IN - 1) { rb = H_IN - 1; wyB = 0.f; }

        const float* rowA = x + ((size_t)bc * H_IN + ra) * W_IN;
        const float* rowB = x + ((size_t)bc * H_IN + rb) * W_IN;

        // input cols c0-2, c0-1, c0, c0+1  (c0+1 <= 127 always)
        const float xA0 = (c0 >= 2) ? rowA[c0 - 2] : 0.f;
        const float xA1 = (c0 >= 1) ? rowA[c0 - 1] : 0.f;
        const float xA2 = rowA[c0];
        const float xA3 = rowA[c0 + 1];
        const float xB0 = (c0 >= 2) ? rowB[c0 - 2] : 0.f;
        const float xB1 = (c0 >= 1) ? rowB[c0 - 1] : 0.f;
        const float xB2 = rowB[c0];
        const float xB3 = rowB[c0 + 1];

        // combine rows
        const float X0 = wyA * xA0 + wyB * xB0;
        const float X1 = wyA * xA1 + wyB * xB1;
        const float X2 = wyA * xA2 + wyB * xB2;
        const float X3 = wyA * xA3 + wyB * xB3;

        // horizontal taps, overall scale 1/16
        float4 o;
        o.x = (X0 + 3.f * X1) * 0.0625f;       // xo even: cols (c0-2,c0-1) w=(1,3)
        o.y = (3.f * X1 + X2) * 0.0625f;       // xo odd : cols (c0-1,c0)  w=(3,1)
        o.z = (X1 + 3.f * X2) * 0.0625f;       // xo even: cols (c0-1,c0)  w=(1,3)
        o.w = (3.f * X2 + X3) * 0.0625f;       // xo odd : cols (c0,c0+1)  w=(3,1)

        const size_t oidx = ((size_t)bc * H2 + y) * W2 + (size_t)c0 * 2;
        *reinterpret_cast<float4*>(out + oidx) = o;
    }
}

extern "C" void kernel_launch(void* const* d_in, const int* in_sizes, int n_in,
                              void* d_out, int out_size, void* d_ws, size_t ws_size,
                              hipStream_t stream) {
    const float* x = (const float*)d_in[0];
    float* out = (float*)d_out;

    const int nQuads = B_ * C_ * H2 * QPR;     // 16,777,216
    dim3 block(256);
    dim3 grid(4096);                            // grid-stride, ~16 iters/thread
    upfir_up2_kernel<<<grid, block, 0, stream>>>(x, out, nQuads);
}

// Round 2
// 86.447 us; speedup vs baseline: 1.2772x; 1.2772x over previous
//
#include <hip/hip_runtime.h>

#define H_IN 128
#define W_IN 128
#define H2 256
#define W2 256
#define WQ 32                        // float4-quads per input row
#define NTHREADS (4*256*H_IN*WQ)     // 4,194,304 threads, one tile each

__global__ __launch_bounds__(256) void upfir_up2_kernel(
    const float* __restrict__ x, float* __restrict__ out)
{
    const int tid = blockIdx.x * 256 + threadIdx.x;
    const int wq = tid & (WQ - 1);          // 0..31
    const int h  = (tid >> 5) & (H_IN - 1); // 0..127
    const int bc = tid >> 12;               // 0..1023
    const int w0 = wq * 4;                  // input col base

    const float* row0 = x + ((size_t)bc * H_IN + h) * W_IN;
    const float* rowm = row0 - W_IN;
    const float* rowp = row0 + W_IN;

    // window: input cols w0-2 .. w0+3 from rows h-1, h, h+1
    float4 c4 = *reinterpret_cast<const float4*>(row0 + w0);
    float4 m4 = {0.f,0.f,0.f,0.f}, p4 = {0.f,0.f,0.f,0.f};
    float2 c2 = {0.f,0.f}, m2 = {0.f,0.f}, p2 = {0.f,0.f};

    if (w0 > 0) c2 = *reinterpret_cast<const float2*>(row0 + w0 - 2);
    if (h > 0) {
        m4 = *reinterpret_cast<const float4*>(rowm + w0);
        if (w0 > 0) m2 = *reinterpret_cast<const float2*>(rowm + w0 - 2);
    }
    if (h < H_IN - 1) {
        p4 = *reinterpret_cast<const float4*>(rowp + w0);
        if (w0 > 0) p2 = *reinterpret_cast<const float2*>(rowp + w0 - 2);
    }

    // vertical combine: top output row (2h)   = 1*row(h-1) + 3*row(h)
    //                   bottom output row(2h+1)= 3*row(h)   + 1*row(h+1)
    float vt0 = m2.x + 3.f*c2.x,  vb0 = 3.f*c2.x + p2.x;
    float vt1 = m2.y + 3.f*c2.y,  vb1 = 3.f*c2.y + p2.y;
    float vt2 = m4.x + 3.f*c4.x,  vb2 = 3.f*c4.x + p4.x;
    float vt3 = m4.y + 3.f*c4.y,  vb3 = 3.f*c4.y + p4.y;
    float vt4 = m4.z + 3.f*c4.z,  vb4 = 3.f*c4.z + p4.z;
    float vt5 = m4.w + 3.f*c4.w,  vb5 = 3.f*c4.w + p4.w;

    // horizontal taps: out[2w0+t], t even: (v[t/2] + 3v[t/2+1])/16
    //                              t odd : (3v[(t+1)/2] + v[(t+1)/2+1])/16
    float4 o0, o1, o2, o3;
    o0.x = (vt0 + 3.f*vt1) * 0.0625f;
    o0.y = (3.f*vt1 + vt2) * 0.0625f;
    o0.z = (vt1 + 3.f*vt2) * 0.0625f;
    o0.w = (3.f*vt2 + vt3) * 0.0625f;
    o1.x = (vt2 + 3.f*vt3) * 0.0625f;
    o1.y = (3.f*vt3 + vt4) * 0.0625f;
    o1.z = (vt3 + 3.f*vt4) * 0.0625f;
    o1.w = (3.f*vt4 + vt5) * 0.0625f;

    o2.x = (vb0 + 3.f*vb1) * 0.0625f;
    o2.y = (3.f*vb1 + vb2) * 0.0625f;
    o2.z = (vb1 + 3.f*vb2) * 0.0625f;
    o2.w = (3.f*vb2 + vb3) * 0.0625f;
    o3.x = (vb2 + 3.f*vb3) * 0.0625f;
    o3.y = (3.f*vb3 + vb4) * 0.0625f;
    o3.z = (vb3 + 3.f*vb4) * 0.0625f;
    o3.w = (3.f*vb4 + vb5) * 0.0625f;

    float* orow0 = out + ((size_t)bc * H2 + 2*h) * W2 + 2*w0;
    float* orow1 = orow0 + W2;
    *reinterpret_cast<float4*>(orow0)     = o0;
    *reinterpret_cast<float4*>(orow0 + 4) = o1;
    *reinterpret_cast<float4*>(orow1)     = o2;
    *reinterpret_cast<float4*>(orow1 + 4) = o3;
}

extern "C" void kernel_launch(void* const* d_in, const int* in_sizes, int n_in,
                              void* d_out, int out_size, void* d_ws, size_t ws_size,
                              hipStream_t stream) {
    const float* x = (const float*)d_in[0];
    float* out = (float*)d_out;
    dim3 block(256);
    dim3 grid(NTHREADS / 256);   // 16384 blocks, one tile per thread
    upfir_up2_kernel<<<grid, block, 0, stream>>>(x, out);
}

// Round 4
// 55.431 us; speedup vs baseline: 1.9918x; 1.5596x over previous
//
#include <hip/hip_runtime.h>

typedef float f32x4 __attribute__((ext_vector_type(4)));

#define H_IN 128
#define W_IN 128
#define H2 256
#define W2 256
#define HH  (H_IN/2)                  // 64 input row-pairs
#define NTHREADS (4*256*HH*64)        // 4,194,304 threads

__global__ __launch_bounds__(256) void upfir_up2_kernel(
    const float* __restrict__ x, float* __restrict__ out)
{
    const int tid  = blockIdx.x * 256 + threadIdx.x;
    const int qcol = tid & 63;              // output col-quad 0..63 (lane id)
    const int hh   = (tid >> 6) & (HH - 1); // input row-pair 0..63
    const int bc   = tid >> 12;             // 0..1023
    const int h    = 2 * hh;                // input row base
    const int ic   = 2 * qcol - 2;          // input col base (may be -2)

    const float* rowc = x + ((size_t)bc * H_IN + h) * W_IN;
    const float* rowm = rowc - W_IN;        // h-1
    const float* rowp = rowc + W_IN;        // h+1
    const float* rowq = rowc + 2 * W_IN;    // h+2

    const bool lane0 = (qcol == 0);

    // load 4 input cols (ic..ic+3) from 4 rows; zero-pad at edges
    f32x4 m, c, p, q;
    if (!lane0) {
        c = *reinterpret_cast<const f32x4*>(rowc + ic);
        p = *reinterpret_cast<const f32x4*>(rowp + ic);
    } else {
        c = (f32x4){0.f, 0.f, rowc[0], rowc[1]};
        p = (f32x4){0.f, 0.f, rowp[0], rowp[1]};
    }
    if (hh > 0) {
        m = (!lane0) ? *reinterpret_cast<const f32x4*>(rowm + ic)
                     : (f32x4){0.f, 0.f, rowm[0], rowm[1]};
    } else {
        m = (f32x4){0.f, 0.f, 0.f, 0.f};
    }
    if (hh < HH - 1) {
        q = (!lane0) ? *reinterpret_cast<const f32x4*>(rowq + ic)
                     : (f32x4){0.f, 0.f, rowq[0], rowq[1]};
    } else {
        q = (f32x4){0.f, 0.f, 0.f, 0.f};
    }

    // vertical taps for 4 output rows:
    // r0 = 1*m + 3*c ; r1 = 3*c + 1*p ; r2 = 1*c + 3*p ; r3 = 3*p + 1*q
    f32x4 v0 = m + 3.f*c;
    f32x4 v1 = 3.f*c + p;
    f32x4 v2 = c + 3.f*p;
    f32x4 v3 = 3.f*p + q;

    // horizontal taps + 1/16 scale; store 4 dense rows
    float* obase = out + ((size_t)bc * H2 + 2*h) * W2 + 4*qcol;
    f32x4 vv[4] = {v0, v1, v2, v3};
    #pragma unroll
    for (int k = 0; k < 4; ++k) {
        f32x4 v = vv[k];
        f32x4 o;
        o.x = (v.x + 3.f*v.y) * 0.0625f;
        o.y = (3.f*v.y + v.z) * 0.0625f;
        o.z = (v.y + 3.f*v.z) * 0.0625f;
        o.w = (3.f*v.z + v.w) * 0.0625f;
        __builtin_nontemporal_store(o, reinterpret_cast<f32x4*>(obase + (size_t)k * W2));
    }
}

extern "C" void kernel_launch(void* const* d_in, const int* in_sizes, int n_in,
                              void* d_out, int out_size, void* d_ws, size_t ws_size,
                              hipStream_t stream) {
    const float* x = (const float*)d_in[0];
    float* out = (float*)d_out;
    dim3 block(256);
    dim3 grid(NTHREADS / 256);   // 16384 blocks
    upfir_up2_kernel<<<grid, block, 0, stream>>>(x, out);
}